// Round 5
// baseline (336.399 us; speedup 1.0000x reference)
//
#include <hip/hip_runtime.h>
#include <hip/hip_bf16.h>
#include <math.h>

#define N_TOK 4096
#define DIM 512
#define IDIM 2048
#define NEXP 8

typedef __attribute__((ext_vector_type(8))) short bf16x8;
typedef __attribute__((ext_vector_type(4))) float floatx4;

__device__ __forceinline__ short f2bf(float f) {
  unsigned int u;
  __builtin_memcpy(&u, &f, 4);
  u += 0x7fff + ((u >> 16) & 1);  // round-to-nearest-even
  return (short)(u >> 16);
}

__device__ __forceinline__ bf16x8 ld8f(const float* __restrict__ p) {
  float4 a = *(const float4*)p;
  float4 b = *(const float4*)(p + 4);
  bf16x8 v;
  v[0] = f2bf(a.x); v[1] = f2bf(a.y); v[2] = f2bf(a.z); v[3] = f2bf(a.w);
  v[4] = f2bf(b.x); v[5] = f2bf(b.y); v[6] = f2bf(b.z); v[7] = f2bf(b.w);
  return v;
}

// async global->LDS DMA, 16B/lane, LDS dest = wave-uniform base + lane*16
__device__ __forceinline__ void gll(const short* g, short* l) {
  __builtin_amdgcn_global_load_lds(
      (const __attribute__((address_space(1))) void*)g,
      (__attribute__((address_space(3))) void*)l, 16, 0, 0);
}

// ---------------- convert fp32 -> bf16: x, w1, w3, sw1, sw2 -----------------
__global__ __launch_bounds__(256) void convert5(
    const float* __restrict__ x, const float* __restrict__ w1,
    const float* __restrict__ w3, const float* __restrict__ sw1,
    const float* __restrict__ sw2, short* __restrict__ xb,
    short* __restrict__ w1b, short* __restrict__ w3b,
    short* __restrict__ sw1b, short* __restrict__ sw2b) {
  const long C0 = 262144, C1 = 1310720, C2 = 2359296, C3 = 2490368, C4 = 2621440;
  for (long i = (long)blockIdx.x * 256 + threadIdx.x; i < C4; i += (long)gridDim.x * 256) {
    const float* s; short* d; long off;
    if (i < C0)      { s = x;   d = xb;   off = i; }
    else if (i < C1) { s = w1;  d = w1b;  off = i - C0; }
    else if (i < C2) { s = w3;  d = w3b;  off = i - C1; }
    else if (i < C3) { s = sw1; d = sw1b; off = i - C2; }
    else             { s = sw2; d = sw2b; off = i - C3; }
    *(bf16x8*)(d + off * 8) = ld8f(s + off * 8);
  }
}

__global__ __launch_bounds__(256) void convert1(
    const float* __restrict__ s, short* __restrict__ d, long nch) {
  for (long i = (long)blockIdx.x * 256 + threadIdx.x; i < nch; i += (long)gridDim.x * 256)
    *(bf16x8*)(d + i * 8) = ld8f(s + i * 8);
}

// ---------------- gate: fp32 logits (fp64 acc) -> argmax expert per token ----
__global__ __launch_bounds__(256) void gate_kernel(
    const float* __restrict__ x, const float* __restrict__ gw,
    int* __restrict__ expert_id, int* __restrict__ counts) {
  int tid = threadIdx.x;
  int trow = tid >> 3;
  int e = tid & 7;
  int tok = blockIdx.x * 32 + trow;
  const float* xr = x + (long)tok * DIM;
  const float* wr = gw + e * DIM;
  double s = 0.0;
  for (int k = 0; k < DIM; k += 4) {
    float4 xv = *(const float4*)(xr + k);
    float4 wv = *(const float4*)(wr + k);
    s += (double)xv.x * wv.x + (double)xv.y * wv.y +
         (double)xv.z * wv.z + (double)xv.w * wv.w;
  }
  __shared__ double lg[32][8];
  lg[trow][e] = s;
  __syncthreads();
  if (e == 0) {
    double best = lg[trow][0];
    int bi = 0;
#pragma unroll
    for (int j = 1; j < 8; j++) {
      double v = lg[trow][j];
      if (v > best) { best = v; bi = j; }
    }
    expert_id[tok] = bi;
    atomicAdd(&counts[bi], 1);
  }
}

// --- scan + tile tables: stage1 (BM=128 routed + shared e=8), stage2 (BM=64) -
__global__ __launch_bounds__(256) void scan_scatter(
    const int* __restrict__ expert_id, const int* __restrict__ counts,
    int* __restrict__ offsets, int* __restrict__ cursors, int* __restrict__ nmeta,
    int* __restrict__ te1, int* __restrict__ tr1,
    int* __restrict__ te2, int* __restrict__ tr2, int* __restrict__ perm) {
  if (threadIdx.x == 0) {
    int acc = 0;
    for (int e = 0; e < NEXP; e++) {
      offsets[e] = acc;
      cursors[e] = acc;
      acc += counts[e];
    }
    int n1 = 0;
    for (int e = 0; e < NEXP; e++)
      for (int r = 0; r < counts[e]; r += 128) { te1[n1] = e; tr1[n1] = r; n1++; }
    for (int r = 0; r < N_TOK; r += 128) { te1[n1] = 8; tr1[n1] = r; n1++; }
    int n2 = 0;
    for (int e = 0; e < NEXP; e++)
      for (int r = 0; r < counts[e]; r += 64) { te2[n2] = e; tr2[n2] = r; n2++; }
    nmeta[0] = n1;  // <= 71
    nmeta[1] = n2;  // <= 71
  }
  __syncthreads();
  for (int t = threadIdx.x; t < N_TOK; t += 256) {
    int e = expert_id[t];
    int slot = atomicAdd(&cursors[e], 1);
    perm[slot] = t;
  }
}

// stage1: routed h = silu(Xe@w1^T)*(Xe@w3^T); shared g = gelu(Xs@sw1^T).
// Both gather A rows via perm => h AND g are in sorted row order.
// BM=128, BN=128, BK=64, XOR-swizzled LDS, global_load_lds staging.
__global__ __launch_bounds__(256) void stage1(
    const short* __restrict__ xb, const short* __restrict__ w1b,
    const short* __restrict__ w3b, const short* __restrict__ sw1b,
    short* __restrict__ h, short* __restrict__ g,
    const int* __restrict__ counts, const int* __restrict__ offsets,
    const int* __restrict__ nmeta, const int* __restrict__ te,
    const int* __restrict__ tr, const int* __restrict__ perm) {
  __shared__ short Al[128 * 64];
  __shared__ short Bl[2][128 * 64];
  int t = blockIdx.y;
  if (t >= nmeta[0]) return;
  int e = te[t], row0 = tr[t];
  bool routed = (e < 8);
  int cnt = routed ? counts[e] : N_TOK;
  int base = routed ? offsets[e] : 0;
  int n0 = blockIdx.x * 128;
  int tid = threadIdx.x, lane = tid & 63, w = tid >> 6;
  int wm = w >> 1, wn = w & 1;
  const short* B1 = routed ? w1b + (long)e * IDIM * DIM : sw1b;
  const short* B2 = routed ? w3b + (long)e * IDIM * DIM : sw1b;

  int aoff[4], boff[4], lb[4];
#pragma unroll
  for (int j = 0; j < 4; j++) {
    int c = w * 256 + j * 64 + lane;
    int row = c >> 3;
    int klog = (c & 7) ^ (row & 7);
    int srow = row0 + row;
    int slot = base + ((srow < cnt) ? srow : (cnt - 1));
    aoff[j] = perm[slot] * DIM + klog * 8;
    boff[j] = (n0 + row) * DIM + klog * 8;
    lb[j] = (w * 256 + j * 64) * 8;
  }

  floatx4 acc[2][4][4];
#pragma unroll
  for (int m = 0; m < 2; m++)
#pragma unroll
    for (int i = 0; i < 4; i++)
#pragma unroll
      for (int j = 0; j < 4; j++) acc[m][i][j] = (floatx4)0.f;

  for (int kc = 0; kc < DIM; kc += 64) {
#pragma unroll
    for (int j = 0; j < 4; j++) gll(xb + aoff[j] + kc, &Al[lb[j]]);
#pragma unroll
    for (int j = 0; j < 4; j++) gll(B1 + boff[j] + kc, &Bl[0][lb[j]]);
    if (routed) {
#pragma unroll
      for (int j = 0; j < 4; j++) gll(B2 + boff[j] + kc, &Bl[1][lb[j]]);
    }
    __syncthreads();

    bf16x8 af[4][2];
#pragma unroll
    for (int mf = 0; mf < 4; mf++)
#pragma unroll
      for (int kf = 0; kf < 2; kf++) {
        int row = wm * 64 + mf * 16 + (lane & 15);
        int kp = (kf * 4 + (lane >> 4)) ^ (lane & 7);
        af[mf][kf] = *(const bf16x8*)&Al[row * 64 + kp * 8];
      }
#pragma unroll
    for (int m = 0; m < 2; m++) {
      if (m == 1 && !routed) break;
#pragma unroll
      for (int nf = 0; nf < 4; nf++)
#pragma unroll
        for (int kf = 0; kf < 2; kf++) {
          int col = wn * 64 + nf * 16 + (lane & 15);
          int kp = (kf * 4 + (lane >> 4)) ^ (lane & 7);
          bf16x8 bv = *(const bf16x8*)&Bl[m][col * 64 + kp * 8];
#pragma unroll
          for (int mf = 0; mf < 4; mf++)
            acc[m][mf][nf] = __builtin_amdgcn_mfma_f32_16x16x32_bf16(
                af[mf][kf], bv, acc[m][mf][nf], 0, 0, 0);
        }
    }
    __syncthreads();
  }

  int quad = lane >> 4;
  int colb = n0 + wn * 64 + (lane & 15);
  short* dst = routed ? h : g;
#pragma unroll
  for (int mf = 0; mf < 4; mf++)
#pragma unroll
    for (int r = 0; r < 4; r++) {
      int srow = row0 + wm * 64 + mf * 16 + quad * 4 + r;
      if (srow >= cnt) continue;
      long ro = (long)(base + srow) * IDIM + colb;
      if (routed) {
#pragma unroll
        for (int nf = 0; nf < 4; nf++) {
          float a1 = acc[0][mf][nf][r];
          float a3 = acc[1][mf][nf][r];
          dst[ro + nf * 16] = f2bf((a1 / (1.f + __expf(-a1))) * a3);
        }
      } else {
#pragma unroll
        for (int nf = 0; nf < 4; nf++) {
          float v = acc[0][mf][nf][r];
          dst[ro + nf * 16] = f2bf(0.5f * v * (1.f + erff(v * 0.70710678118f)));
        }
      }
    }
}

// stage2: out[perm[rows]] = He@w2^T + Ge@sw2^T. One write per out element:
// no atomics, no split-K. BM=64, BN=64, two K-loops (K=2048 each) share acc.
__global__ __launch_bounds__(256) void stage2(
    const short* __restrict__ h, const short* __restrict__ g,
    const short* __restrict__ w2b, const short* __restrict__ sw2b,
    float* __restrict__ out, const int* __restrict__ counts,
    const int* __restrict__ offsets, const int* __restrict__ nmeta,
    const int* __restrict__ te, const int* __restrict__ tr,
    const int* __restrict__ perm) {
  __shared__ short Al[64 * 64];
  __shared__ short Bl[64 * 64];
  int t = blockIdx.y;
  if (t >= nmeta[1]) return;
  int e = te[t], row0 = tr[t];
  int cnt = counts[e], base = offsets[e];
  int n0 = blockIdx.x * 64;
  int tid = threadIdx.x, lane = tid & 63, w = tid >> 6;
  int wm = w >> 1, wn = w & 1;

  int aoff[2], boff[2], lb[2];
#pragma unroll
  for (int j = 0; j < 2; j++) {
    int c = w * 128 + j * 64 + lane;
    int row = c >> 3;
    int klog = (c & 7) ^ (row & 7);
    int srow = row0 + row;
    int arow = base + ((srow < cnt) ? srow : (cnt - 1));
    aoff[j] = arow * IDIM + klog * 8;
    boff[j] = (n0 + row) * IDIM + klog * 8;
    lb[j] = (w * 128 + j * 64) * 8;
  }

  floatx4 acc[2][2];
#pragma unroll
  for (int i = 0; i < 2; i++)
#pragma unroll
    for (int j = 0; j < 2; j++) acc[i][j] = (floatx4)0.f;

#pragma unroll
  for (int ph = 0; ph < 2; ph++) {
    const short* As = ph ? g : h;
    const short* Bs = ph ? sw2b : w2b + (long)e * DIM * IDIM;
    for (int kc = 0; kc < IDIM; kc += 64) {
#pragma unroll
      for (int j = 0; j < 2; j++) gll(As + aoff[j] + kc, &Al[lb[j]]);
#pragma unroll
      for (int j = 0; j < 2; j++) gll(Bs + boff[j] + kc, &Bl[lb[j]]);
      __syncthreads();

      bf16x8 af[2][2];
#pragma unroll
      for (int mf = 0; mf < 2; mf++)
#pragma unroll
        for (int kf = 0; kf < 2; kf++) {
          int row = wm * 32 + mf * 16 + (lane & 15);
          int kp = (kf * 4 + (lane >> 4)) ^ (lane & 7);
          af[mf][kf] = *(const bf16x8*)&Al[row * 64 + kp * 8];
        }
#pragma unroll
      for (int nf = 0; nf < 2; nf++)
#pragma unroll
        for (int kf = 0; kf < 2; kf++) {
          int col = wn * 32 + nf * 16 + (lane & 15);
          int kp = (kf * 4 + (lane >> 4)) ^ (lane & 7);
          bf16x8 bv = *(const bf16x8*)&Bl[col * 64 + kp * 8];
#pragma unroll
          for (int mf = 0; mf < 2; mf++)
            acc[mf][nf] = __builtin_amdgcn_mfma_f32_16x16x32_bf16(
                af[mf][kf], bv, acc[mf][nf], 0, 0, 0);
        }
      __syncthreads();
    }
  }

  int quad = lane >> 4;
  int colb = n0 + wn * 32 + (lane & 15);
#pragma unroll
  for (int mf = 0; mf < 2; mf++)
#pragma unroll
    for (int r = 0; r < 4; r++) {
      int srow = row0 + wm * 32 + mf * 16 + quad * 4 + r;
      if (srow >= cnt) continue;
      long ro = (long)perm[base + srow] * DIM + colb;
#pragma unroll
      for (int nf = 0; nf < 2; nf++) out[ro + nf * 16] = acc[mf][nf][r];
    }
}

extern "C" void kernel_launch(void* const* d_in, const int* in_sizes, int n_in,
                              void* d_out, int out_size, void* d_ws, size_t ws_size,
                              hipStream_t stream) {
  const float* x = (const float*)d_in[0];
  const float* gate_w = (const float*)d_in[1];
  const float* w1 = (const float*)d_in[2];
  const float* w2 = (const float*)d_in[3];
  const float* w3 = (const float*)d_in[4];
  const float* sw1 = (const float*)d_in[5];
  const float* sw2 = (const float*)d_in[6];
  float* out = (float*)d_out;

  char* ws = (char*)d_ws;
  int* counts = (int*)ws;          // 8
  int* offsets = counts + 8;       // 8
  int* cursors = offsets + 8;      // 8
  int* nmeta = cursors + 8;        // 8
  int* te1 = nmeta + 8;            // 128
  int* tr1 = te1 + 128;            // 128
  int* te2 = tr1 + 128;            // 128
  int* tr2 = te2 + 128;            // 128
  int* expert_id = tr2 + 128;      // 4096
  int* perm = expert_id + N_TOK;   // 4096
  short* xb = (short*)(ws + 65536);                 // 4 MB   [N_TOK, DIM]
  short* h = xb + (size_t)N_TOK * DIM;              // 16 MB  [N_TOK, IDIM] sorted
  short* g = h + (size_t)N_TOK * IDIM;              // 16 MB  [N_TOK, IDIM] sorted
  short* w1b = g + (size_t)N_TOK * IDIM;            // 16 MB  (aliased by w2b later)
  short* w3b = w1b + (size_t)NEXP * IDIM * DIM;     // 16 MB
  short* sw1b = w3b + (size_t)NEXP * IDIM * DIM;    // 2 MB
  short* sw2b = sw1b + (size_t)IDIM * DIM;          // 2 MB
  short* w2b = w1b;  // reuse: w1b dead after stage1

  hipMemsetAsync(counts, 0, 8 * sizeof(int), stream);
  gate_kernel<<<N_TOK / 32, 256, 0, stream>>>(x, gate_w, expert_id, counts);
  scan_scatter<<<1, 256, 0, stream>>>(expert_id, counts, offsets, cursors, nmeta,
                                      te1, tr1, te2, tr2, perm);
  convert5<<<2560, 256, 0, stream>>>(x, w1, w3, sw1, sw2, xb, w1b, w3b, sw1b, sw2b);
  stage1<<<dim3(IDIM / 128, 72), 256, 0, stream>>>(
      xb, w1b, w3b, sw1b, h, g, counts, offsets, nmeta, te1, tr1, perm);
  convert1<<<2048, 256, 0, stream>>>(w2, w2b, (long)NEXP * DIM * IDIM / 8);
  stage2<<<dim3(DIM / 64, 72), 256, 0, stream>>>(
      h, g, w2b, sw2b, out, counts, offsets, nmeta, te2, tr2, perm);
}

// Round 6
// 334.392 us; speedup vs baseline: 1.0060x; 1.0060x over previous
//
#include <hip/hip_runtime.h>
#include <hip/hip_bf16.h>
#include <math.h>

#define N_TOK 4096
#define DIM 512
#define IDIM 2048
#define NEXP 8

typedef __attribute__((ext_vector_type(8))) short bf16x8;
typedef __attribute__((ext_vector_type(4))) float floatx4;

#define WAITV(N) asm volatile("s_waitcnt vmcnt(" #N ")" ::: "memory")
#define BARRIER() asm volatile("s_barrier" ::: "memory")

__device__ __forceinline__ short f2bf(float f) {
  unsigned int u;
  __builtin_memcpy(&u, &f, 4);
  u += 0x7fff + ((u >> 16) & 1);  // round-to-nearest-even
  return (short)(u >> 16);
}

__device__ __forceinline__ bf16x8 ld8f(const float* __restrict__ p) {
  float4 a = *(const float4*)p;
  float4 b = *(const float4*)(p + 4);
  bf16x8 v;
  v[0] = f2bf(a.x); v[1] = f2bf(a.y); v[2] = f2bf(a.z); v[3] = f2bf(a.w);
  v[4] = f2bf(b.x); v[5] = f2bf(b.y); v[6] = f2bf(b.z); v[7] = f2bf(b.w);
  return v;
}

// cheap exact-enough erf: Abramowitz-Stegun 7.1.26, |err| <= 1.5e-7
__device__ __forceinline__ float gelu_exactish(float v) {
  float z = fabsf(v) * 0.70710678118f;
  float tt = 1.f / (1.f + 0.3275911f * z);
  float poly = tt * (0.254829592f + tt * (-0.284496736f + tt * (1.421413741f +
               tt * (-1.453152027f + tt * 1.061405429f))));
  float er = 1.f - poly * __expf(-z * z);
  er = (v < 0.f) ? -er : er;
  return 0.5f * v * (1.f + er);
}

// async global->LDS DMA, 16B/lane, LDS dest = wave-uniform base + lane*16
__device__ __forceinline__ void gll(const short* g, short* l) {
  __builtin_amdgcn_global_load_lds(
      (const __attribute__((address_space(1))) void*)g,
      (__attribute__((address_space(3))) void*)l, 16, 0, 0);
}

// ---- gate: read x once, write xb (bf16), fp32-in-LDS dot w/ fp64 acc -------
__global__ __launch_bounds__(256) void gate_kernel(
    const float* __restrict__ x, const float* __restrict__ gw,
    short* __restrict__ xb, int* __restrict__ expert_id, int* __restrict__ counts) {
  __shared__ float xs[16 * 516];   // 16 tokens, padded stride
  __shared__ double ps[16][8][2];
  int t = threadIdx.x;
  int tok0 = blockIdx.x * 16;
  const float* xrow = x + (long)tok0 * DIM;
  for (int i = t; i < 2048; i += 256) {  // i indexes float4
    float4 v = ((const float4*)xrow)[i];
    int row = i >> 7, c4 = i & 127;
    *(float4*)&xs[row * 516 + c4 * 4] = v;
    short4 b;
    b.x = f2bf(v.x); b.y = f2bf(v.y); b.z = f2bf(v.z); b.w = f2bf(v.w);
    *(short4*)(xb + (long)tok0 * DIM + i * 4) = b;
  }
  __syncthreads();
  int tok = t & 15, e = (t >> 4) & 7, hf = t >> 7;
  const float* xr = &xs[tok * 516 + hf * 256];
  const float* wr = gw + e * DIM + hf * 256;
  double s = 0.0;
  for (int k = 0; k < 256; k += 4) {
    float4 xv = *(const float4*)(xr + k);
    float4 wv = *(const float4*)(wr + k);
    s += (double)xv.x * wv.x + (double)xv.y * wv.y +
         (double)xv.z * wv.z + (double)xv.w * wv.w;
  }
  ps[tok][e][hf] = s;
  __syncthreads();
  if (t < 16) {
    double best = ps[t][0][0] + ps[t][0][1];
    int bi = 0;
#pragma unroll
    for (int j = 1; j < 8; j++) {  // strict > keeps lowest index on ties
      double v = ps[t][j][0] + ps[t][j][1];
      if (v > best) { best = v; bi = j; }
    }
    expert_id[tok0 + t] = bi;
    atomicAdd(&counts[bi], 1);
  }
}

// ---- scan + tile tables: stage1 (BM=128 routed + shared e=8), stage2 (BM=64)
__global__ __launch_bounds__(256) void scan_scatter(
    const int* __restrict__ expert_id, const int* __restrict__ counts,
    int* __restrict__ offsets, int* __restrict__ cursors, int* __restrict__ nmeta,
    int* __restrict__ te1, int* __restrict__ tr1,
    int* __restrict__ te2, int* __restrict__ tr2, int* __restrict__ perm) {
  if (threadIdx.x == 0) {
    int acc = 0;
    for (int e = 0; e < NEXP; e++) {
      offsets[e] = acc;
      cursors[e] = acc;
      acc += counts[e];
    }
    int n1 = 0;
    for (int e = 0; e < NEXP; e++)
      for (int r = 0; r < counts[e]; r += 128) { te1[n1] = e; tr1[n1] = r; n1++; }
    for (int r = 0; r < N_TOK; r += 128) { te1[n1] = 8; tr1[n1] = r; n1++; }
    int n2 = 0;
    for (int e = 0; e < NEXP; e++)
      for (int r = 0; r < counts[e]; r += 64) { te2[n2] = e; tr2[n2] = r; n2++; }
    nmeta[0] = n1;
    nmeta[1] = n2;
  }
  __syncthreads();
  for (int t = threadIdx.x; t < N_TOK; t += 256) {
    int e = expert_id[t];
    int slot = atomicAdd(&cursors[e], 1);
    perm[slot] = t;
  }
}

// ---- convert weights fp32 -> bf16 ------------------------------------------
__global__ __launch_bounds__(256) void convert4(
    const float* __restrict__ w1, const float* __restrict__ w3,
    const float* __restrict__ sw1, const float* __restrict__ sw2,
    short* __restrict__ w1b, short* __restrict__ w3b,
    short* __restrict__ sw1b, short* __restrict__ sw2b) {
  const long C1 = 1048576, C2 = 2097152, C3 = 2228224, C4 = 2359296;
  for (long i = (long)blockIdx.x * 256 + threadIdx.x; i < C4; i += (long)gridDim.x * 256) {
    const float* s; short* d; long off;
    if (i < C1)      { s = w1;  d = w1b;  off = i; }
    else if (i < C2) { s = w3;  d = w3b;  off = i - C1; }
    else if (i < C3) { s = sw1; d = sw1b; off = i - C2; }
    else             { s = sw2; d = sw2b; off = i - C3; }
    *(bf16x8*)(d + off * 8) = ld8f(s + off * 8);
  }
}

__global__ __launch_bounds__(256) void convert1(
    const float* __restrict__ s, short* __restrict__ d, long nch) {
  for (long i = (long)blockIdx.x * 256 + threadIdx.x; i < nch; i += (long)gridDim.x * 256)
    *(bf16x8*)(d + i * 8) = ld8f(s + i * 8);
}

// ---- stage1: h = silu(Xe@w1^T)*(Xe@w3^T); g = gelu(Xs@sw1^T), sorted rows --
// BM=128 BN=128 BK=32, double-buffered LDS, manual vmcnt + raw barriers.
// 32-elem rows are natively conflict-free (frag reads are dense 1KB perms).
__global__ __launch_bounds__(256) void stage1(
    const short* __restrict__ xb, const short* __restrict__ w1b,
    const short* __restrict__ w3b, const short* __restrict__ sw1b,
    short* __restrict__ h, short* __restrict__ g,
    const int* __restrict__ counts, const int* __restrict__ offsets,
    const int* __restrict__ nmeta, const int* __restrict__ te,
    const int* __restrict__ tr, const int* __restrict__ perm) {
  __shared__ short Al[2][128 * 32];
  __shared__ short B1l[2][128 * 32];
  __shared__ short B2l[2][128 * 32];
  int t = blockIdx.y;
  if (t >= nmeta[0]) return;
  int e = te[t], row0 = tr[t];
  bool routed = (e < 8);
  int cnt = routed ? counts[e] : N_TOK;
  int base = routed ? offsets[e] : 0;
  int n0 = blockIdx.x * 128;
  int tid = threadIdx.x, lane = tid & 63, w = tid >> 6;
  int wm = w >> 1, wn = w & 1;
  const short* B1 = routed ? w1b + (long)e * IDIM * DIM : sw1b;
  const short* B2 = w3b + (long)e * IDIM * DIM;

  int aoff[2], boff[2], lb[2];
#pragma unroll
  for (int j = 0; j < 2; j++) {
    int r = (w * 2 + j) * 16 + (lane >> 2);
    int srow = row0 + r;
    int slot = base + ((srow < cnt) ? srow : (cnt - 1));
    aoff[j] = perm[slot] * DIM + (lane & 3) * 8;
    boff[j] = (n0 + r) * DIM + (lane & 3) * 8;
    lb[j] = (w * 2 + j) * 512;  // shorts
  }

  floatx4 acc[2][4][4];
#pragma unroll
  for (int m = 0; m < 2; m++)
#pragma unroll
    for (int i = 0; i < 4; i++)
#pragma unroll
      for (int j = 0; j < 4; j++) acc[m][i][j] = (floatx4)0.f;

  // prologue: kc=0 -> buf0
#pragma unroll
  for (int j = 0; j < 2; j++) gll(xb + aoff[j], &Al[0][lb[j]]);
#pragma unroll
  for (int j = 0; j < 2; j++) gll(B1 + boff[j], &B1l[0][lb[j]]);
  if (routed) {
#pragma unroll
    for (int j = 0; j < 2; j++) gll(B2 + boff[j], &B2l[0][lb[j]]);
  }

  for (int it = 0; it < 16; ++it) {
    if (it < 15) {
      int kc = (it + 1) * 32;
      int b2 = (it + 1) & 1;
#pragma unroll
      for (int j = 0; j < 2; j++) gll(xb + aoff[j] + kc, &Al[b2][lb[j]]);
#pragma unroll
      for (int j = 0; j < 2; j++) gll(B1 + boff[j] + kc, &B1l[b2][lb[j]]);
      if (routed) {
#pragma unroll
        for (int j = 0; j < 2; j++) gll(B2 + boff[j] + kc, &B2l[b2][lb[j]]);
        WAITV(6);
      } else {
        WAITV(4);
      }
    } else {
      WAITV(0);
    }
    BARRIER();
    int b = it & 1;
    bf16x8 af[4];
#pragma unroll
    for (int mf = 0; mf < 4; mf++) {
      int row = wm * 64 + mf * 16 + (lane & 15);
      af[mf] = *(const bf16x8*)&Al[b][row * 32 + (lane >> 4) * 8];
    }
#pragma unroll
    for (int nf = 0; nf < 4; nf++) {
      int col = wn * 64 + nf * 16 + (lane & 15);
      bf16x8 bv = *(const bf16x8*)&B1l[b][col * 32 + (lane >> 4) * 8];
#pragma unroll
      for (int mf = 0; mf < 4; mf++)
        acc[0][mf][nf] = __builtin_amdgcn_mfma_f32_16x16x32_bf16(
            af[mf], bv, acc[0][mf][nf], 0, 0, 0);
    }
    if (routed) {
#pragma unroll
      for (int nf = 0; nf < 4; nf++) {
        int col = wn * 64 + nf * 16 + (lane & 15);
        bf16x8 bv = *(const bf16x8*)&B2l[b][col * 32 + (lane >> 4) * 8];
#pragma unroll
        for (int mf = 0; mf < 4; mf++)
          acc[1][mf][nf] = __builtin_amdgcn_mfma_f32_16x16x32_bf16(
              af[mf], bv, acc[1][mf][nf], 0, 0, 0);
      }
    }
    BARRIER();
  }

  // epilogue: C/D mapping col = lane&15, row = quad*4 + reg
  int quad = lane >> 4;
  int colb = n0 + wn * 64 + (lane & 15);
  short* dst = routed ? h : g;
#pragma unroll
  for (int mf = 0; mf < 4; mf++)
#pragma unroll
    for (int r = 0; r < 4; r++) {
      int srow = row0 + wm * 64 + mf * 16 + quad * 4 + r;
      if (srow >= cnt) continue;
      long ro = (long)(base + srow) * IDIM + colb;
      if (routed) {
#pragma unroll
        for (int nf = 0; nf < 4; nf++) {
          float a1 = acc[0][mf][nf][r];
          float a3 = acc[1][mf][nf][r];
          dst[ro + nf * 16] = f2bf((a1 / (1.f + __expf(-a1))) * a3);
        }
      } else {
#pragma unroll
        for (int nf = 0; nf < 4; nf++)
          dst[ro + nf * 16] = f2bf(gelu_exactish(acc[0][mf][nf][r]));
      }
    }
}

// ---- stage2: out[perm[rows]] = He@w2^T + Ge@sw2^T, BM=64 BN=64 BK=64 dbuf --
__global__ __launch_bounds__(256) void stage2(
    const short* __restrict__ h, const short* __restrict__ g,
    const short* __restrict__ w2b, const short* __restrict__ sw2b,
    float* __restrict__ out, const int* __restrict__ counts,
    const int* __restrict__ offsets, const int* __restrict__ nmeta,
    const int* __restrict__ te, const int* __restrict__ tr,
    const int* __restrict__ perm) {
  __shared__ short Al[2][64 * 64];
  __shared__ short Bl[2][64 * 64];
  int t = blockIdx.y;
  if (t >= nmeta[1]) return;
  int e = te[t], row0 = tr[t];
  int cnt = counts[e], base = offsets[e];
  const short* w2e = w2b + (long)e * DIM * IDIM;
  int n0 = blockIdx.x * 64;
  int tid = threadIdx.x, lane = tid & 63, w = tid >> 6;
  int wm = w >> 1, wn = w & 1;

  int aoff[2], boff[2], lb[2];
#pragma unroll
  for (int j = 0; j < 2; j++) {
    int c = w * 128 + j * 64 + lane;
    int row = c >> 3;
    int klog = (c & 7) ^ (row & 7);  // proven-0-conflict XOR swizzle (R4/R5)
    int srow = row0 + row;
    int arow = base + ((srow < cnt) ? srow : (cnt - 1));
    aoff[j] = arow * IDIM + klog * 8;
    boff[j] = (n0 + row) * IDIM + klog * 8;
    lb[j] = (w * 128 + j * 64) * 8;  // shorts
  }

  floatx4 acc[2][2];
#pragma unroll
  for (int i = 0; i < 2; i++)
#pragma unroll
    for (int j = 0; j < 2; j++) acc[i][j] = (floatx4)0.f;

  // prologue: it=0 (phase h, kc=0) -> buf0
#pragma unroll
  for (int j = 0; j < 2; j++) gll(h + aoff[j], &Al[0][lb[j]]);
#pragma unroll
  for (int j = 0; j < 2; j++) gll(w2e + boff[j], &Bl[0][lb[j]]);

  for (int it = 0; it < 64; ++it) {
    if (it < 63) {
      int itn = it + 1;
      const short* As2 = (itn >> 5) ? g : h;
      const short* Bs2 = (itn >> 5) ? sw2b : w2e;
      int kc2 = (itn & 31) * 64;
      int b2 = itn & 1;
#pragma unroll
      for (int j = 0; j < 2; j++) gll(As2 + aoff[j] + kc2, &Al[b2][lb[j]]);
#pragma unroll
      for (int j = 0; j < 2; j++) gll(Bs2 + boff[j] + kc2, &Bl[b2][lb[j]]);
      WAITV(4);
    } else {
      WAITV(0);
    }
    BARRIER();
    int b = it & 1;
    bf16x8 af[2][2];
#pragma unroll
    for (int mf = 0; mf < 2; mf++)
#pragma unroll
      for (int kf = 0; kf < 2; kf++) {
        int row = wm * 32 + mf * 16 + (lane & 15);
        int kp = (kf * 4 + (lane >> 4)) ^ (lane & 7);
        af[mf][kf] = *(const bf16x8*)&Al[b][row * 64 + kp * 8];
      }
#pragma unroll
    for (int nf = 0; nf < 2; nf++)
#pragma unroll
      for (int kf = 0; kf < 2; kf++) {
        int col = wn * 32 + nf * 16 + (lane & 15);
        int kp = (kf * 4 + (lane >> 4)) ^ (lane & 7);
        bf16x8 bv = *(const bf16x8*)&Bl[b][col * 64 + kp * 8];
#pragma unroll
        for (int mf = 0; mf < 2; mf++)
          acc[mf][nf] = __builtin_amdgcn_mfma_f32_16x16x32_bf16(
              af[mf][kf], bv, acc[mf][nf], 0, 0, 0);
      }
    BARRIER();
  }

  int quad = lane >> 4;
  int colb = n0 + wn * 32 + (lane & 15);
#pragma unroll
  for (int mf = 0; mf < 2; mf++)
#pragma unroll
    for (int r = 0; r < 4; r++) {
      int srow = row0 + wm * 32 + mf * 16 + quad * 4 + r;
      if (srow >= cnt) continue;
      long ro = (long)perm[base + srow] * DIM + colb;
#pragma unroll
      for (int nf = 0; nf < 2; nf++) out[ro + nf * 16] = acc[mf][nf][r];
    }
}

extern "C" void kernel_launch(void* const* d_in, const int* in_sizes, int n_in,
                              void* d_out, int out_size, void* d_ws, size_t ws_size,
                              hipStream_t stream) {
  const float* x = (const float*)d_in[0];
  const float* gate_w = (const float*)d_in[1];
  const float* w1 = (const float*)d_in[2];
  const float* w2 = (const float*)d_in[3];
  const float* w3 = (const float*)d_in[4];
  const float* sw1 = (const float*)d_in[5];
  const float* sw2 = (const float*)d_in[6];
  float* out = (float*)d_out;

  char* ws = (char*)d_ws;
  int* counts = (int*)ws;          // 8
  int* offsets = counts + 8;       // 8
  int* cursors = offsets + 8;      // 8
  int* nmeta = cursors + 8;        // 8
  int* te1 = nmeta + 8;            // 128
  int* tr1 = te1 + 128;            // 128
  int* te2 = tr1 + 128;            // 128
  int* tr2 = te2 + 128;            // 128
  int* expert_id = tr2 + 128;      // 4096
  int* perm = expert_id + N_TOK;   // 4096
  short* xb = (short*)(ws + 65536);                 // 4 MB   [N_TOK, DIM]
  short* h = xb + (size_t)N_TOK * DIM;              // 16 MB  sorted rows
  short* g = h + (size_t)N_TOK * IDIM;              // 16 MB  sorted rows
  short* w1b = g + (size_t)N_TOK * IDIM;            // 16 MB  (aliased by w2b)
  short* w3b = w1b + (size_t)NEXP * IDIM * DIM;     // 16 MB
  short* sw1b = w3b + (size_t)NEXP * IDIM * DIM;    // 2 MB
  short* sw2b = sw1b + (size_t)IDIM * DIM;          // 2 MB
  short* w2b = w1b;  // reuse: w1b dead after stage1

  hipMemsetAsync(counts, 0, 8 * sizeof(int), stream);
  gate_kernel<<<N_TOK / 16, 256, 0, stream>>>(x, gate_w, xb, expert_id, counts);
  scan_scatter<<<1, 256, 0, stream>>>(expert_id, counts, offsets, cursors, nmeta,
                                      te1, tr1, te2, tr2, perm);
  convert4<<<2560, 256, 0, stream>>>(w1, w3, sw1, sw2, w1b, w3b, sw1b, sw2b);
  stage1<<<dim3(IDIM / 128, 72), 256, 0, stream>>>(
      xb, w1b, w3b, sw1b, h, g, counts, offsets, nmeta, te1, tr1, perm);
  convert1<<<2048, 256, 0, stream>>>(w2, w2b, (long)NEXP * DIM * IDIM / 8);
  stage2<<<dim3(DIM / 64, 72), 256, 0, stream>>>(
      h, g, w2b, sw2b, out, counts, offsets, nmeta, te2, tr2, perm);
}

// Round 7
// 304.264 us; speedup vs baseline: 1.1056x; 1.0990x over previous
//
#include <hip/hip_runtime.h>
#include <hip/hip_bf16.h>
#include <math.h>

#define N_TOK 4096
#define DIM 512
#define IDIM 2048
#define NEXP 8

typedef __attribute__((ext_vector_type(8))) short bf16x8;
typedef __attribute__((ext_vector_type(4))) float floatx4;

__device__ __forceinline__ short f2bf(float f) {
  unsigned int u;
  __builtin_memcpy(&u, &f, 4);
  u += 0x7fff + ((u >> 16) & 1);  // round-to-nearest-even
  return (short)(u >> 16);
}

__device__ __forceinline__ bf16x8 ld8f(const float* __restrict__ p) {
  float4 a = *(const float4*)p;
  float4 b = *(const float4*)(p + 4);
  bf16x8 v;
  v[0] = f2bf(a.x); v[1] = f2bf(a.y); v[2] = f2bf(a.z); v[3] = f2bf(a.w);
  v[4] = f2bf(b.x); v[5] = f2bf(b.y); v[6] = f2bf(b.z); v[7] = f2bf(b.w);
  return v;
}

// cheap exact-enough erf: Abramowitz-Stegun 7.1.26, |err| <= 1.5e-7
__device__ __forceinline__ float gelu_exactish(float v) {
  float z = fabsf(v) * 0.70710678118f;
  float tt = 1.f / (1.f + 0.3275911f * z);
  float poly = tt * (0.254829592f + tt * (-0.284496736f + tt * (1.421413741f +
               tt * (-1.453152027f + tt * 1.061405429f))));
  float er = 1.f - poly * __expf(-z * z);
  er = (v < 0.f) ? -er : er;
  return 0.5f * v * (1.f + er);
}

// async global->LDS DMA, 16B/lane, LDS dest = wave-uniform base + lane*16
__device__ __forceinline__ void gll(const short* g, short* l) {
  __builtin_amdgcn_global_load_lds(
      (const __attribute__((address_space(1))) void*)g,
      (__attribute__((address_space(3))) void*)l, 16, 0, 0);
}

// ---- gate: read x once, write xb (bf16), fp32-in-LDS dot w/ fp64 acc -------
__global__ __launch_bounds__(256) void gate_kernel(
    const float* __restrict__ x, const float* __restrict__ gw,
    short* __restrict__ xb, int* __restrict__ expert_id) {
  __shared__ float xs[16 * 516];   // 16 tokens, padded stride
  __shared__ double ps[16][8][2];
  int t = threadIdx.x;
  int tok0 = blockIdx.x * 16;
  const float* xrow = x + (long)tok0 * DIM;
  for (int i = t; i < 2048; i += 256) {  // i indexes float4
    float4 v = ((const float4*)xrow)[i];
    int row = i >> 7, c4 = i & 127;
    *(float4*)&xs[row * 516 + c4 * 4] = v;
    short4 b;
    b.x = f2bf(v.x); b.y = f2bf(v.y); b.z = f2bf(v.z); b.w = f2bf(v.w);
    *(short4*)(xb + (long)tok0 * DIM + i * 4) = b;
  }
  __syncthreads();
  int tok = t & 15, e = (t >> 4) & 7, hf = t >> 7;
  const float* xr = &xs[tok * 516 + hf * 256];
  const float* wr = gw + e * DIM + hf * 256;
  double s = 0.0;
  for (int k = 0; k < 256; k += 4) {
    float4 xv = *(const float4*)(xr + k);
    float4 wv = *(const float4*)(wr + k);
    s += (double)xv.x * wv.x + (double)xv.y * wv.y +
         (double)xv.z * wv.z + (double)xv.w * wv.w;
  }
  ps[tok][e][hf] = s;
  __syncthreads();
  if (t < 16) {
    double best = ps[t][0][0] + ps[t][0][1];
    int bi = 0;
#pragma unroll
    for (int j = 1; j < 8; j++) {  // strict > keeps lowest index on ties
      double v = ps[t][j][0] + ps[t][j][1];
      if (v > best) { best = v; bi = j; }
    }
    expert_id[tok0 + t] = bi;
  }
}

// ---- scan: histogram + offsets + tile tables + perm scatter (1 block) ------
__global__ __launch_bounds__(256) void scan_scatter(
    const int* __restrict__ expert_id, int* __restrict__ counts,
    int* __restrict__ offsets, int* __restrict__ cursors, int* __restrict__ nmeta,
    int* __restrict__ te1, int* __restrict__ tr1,
    int* __restrict__ te2, int* __restrict__ tr2, int* __restrict__ perm) {
  __shared__ int cnt[8];
  int tid = threadIdx.x;
  if (tid < 8) cnt[tid] = 0;
  __syncthreads();
  for (int t = tid; t < N_TOK; t += 256) atomicAdd(&cnt[expert_id[t]], 1);
  __syncthreads();
  if (tid == 0) {
    int acc = 0;
    for (int e = 0; e < NEXP; e++) {
      counts[e] = cnt[e];
      offsets[e] = acc;
      cursors[e] = acc;
      acc += cnt[e];
    }
    int n1 = 0;
    for (int e = 0; e < NEXP; e++)
      for (int r = 0; r < cnt[e]; r += 128) { te1[n1] = e; tr1[n1] = r; n1++; }
    for (int r = 0; r < N_TOK; r += 128) { te1[n1] = 8; tr1[n1] = r; n1++; }
    int n2 = 0;
    for (int e = 0; e < NEXP; e++)
      for (int r = 0; r < cnt[e]; r += 64) { te2[n2] = e; tr2[n2] = r; n2++; }
    nmeta[0] = n1;  // <= 71
    nmeta[1] = n2;  // <= 71
  }
  __syncthreads();
  for (int t = tid; t < N_TOK; t += 256) {
    int e = expert_id[t];
    int slot = atomicAdd(&cursors[e], 1);
    perm[slot] = t;
  }
}

// ---- stage1: h = silu(Xe@w1^T)*(Xe@w3^T); g = gelu(Xs@sw1^T), sorted rows --
// BM=128 BN=64 dual-B BK=64. A: bf16 via global_load_lds. B: fp32 loaded
// in-register, converted, ds_write to the SAME XOR-swizzled linear layout
// (proven 0-conflict in R4/R5). Single LDS buffer, 32KB, 4 blocks/CU.
__global__ __launch_bounds__(256, 4) void stage1(
    const short* __restrict__ xb, const float* __restrict__ w1,
    const float* __restrict__ w3, const float* __restrict__ sw1,
    short* __restrict__ h, short* __restrict__ g,
    const int* __restrict__ counts, const int* __restrict__ offsets,
    const int* __restrict__ nmeta, const int* __restrict__ te,
    const int* __restrict__ tr, const int* __restrict__ perm) {
  __shared__ short Al[128 * 64];
  __shared__ short B1l[64 * 64];
  __shared__ short B2l[64 * 64];
  int t = blockIdx.y;
  if (t >= nmeta[0]) return;
  int e = te[t], row0 = tr[t];
  bool routed = (e < 8);
  int cnt = routed ? counts[e] : N_TOK;
  int base = routed ? offsets[e] : 0;
  int n0 = blockIdx.x * 64;
  int tid = threadIdx.x, lane = tid & 63, w = tid >> 6;
  int wm = w >> 1, wn = w & 1;
  const float* B1 = routed ? w1 + (long)e * IDIM * DIM : sw1;
  const float* B2 = w3 + (long)e * IDIM * DIM;  // never dereferenced if !routed

  // A: 1024 chunks of 8 bf16, 4 gll/thread, klog-swizzle in global addr
  int aoff[4], lbA[4];
#pragma unroll
  for (int j = 0; j < 4; j++) {
    int c = w * 256 + j * 64 + lane;
    int row = c >> 3, klog = (c & 7) ^ (row & 7);
    int srow = row0 + row;
    int slot = base + ((srow < cnt) ? srow : (cnt - 1));
    aoff[j] = perm[slot] * DIM + klog * 8;
    lbA[j] = (w * 256 + j * 64) * 8;  // wave-uniform base (shorts)
  }
  // B: 512 chunks per matrix, 2/thread; fp32 global at klog granule
  int bgoff[2], lbB[2];
#pragma unroll
  for (int i = 0; i < 2; i++) {
    int c = i * 256 + tid;
    int row = c >> 3, klog = (c & 7) ^ (row & 7);
    bgoff[i] = (n0 + row) * DIM + klog * 8;  // fp32 elements
    lbB[i] = c * 8;                          // linear (shorts) => conflict-free write
  }

  floatx4 acc[2][4][2];
#pragma unroll
  for (int m = 0; m < 2; m++)
#pragma unroll
    for (int i = 0; i < 4; i++)
#pragma unroll
      for (int j = 0; j < 2; j++) acc[m][i][j] = (floatx4)0.f;

  for (int kc = 0; kc < DIM; kc += 64) {
#pragma unroll
    for (int j = 0; j < 4; j++) gll(xb + aoff[j] + kc, &Al[lbA[j]]);
#pragma unroll
    for (int i = 0; i < 2; i++) {
      *(bf16x8*)&B1l[lbB[i]] = ld8f(B1 + bgoff[i] + kc);
    }
    if (routed) {
#pragma unroll
      for (int i = 0; i < 2; i++) {
        *(bf16x8*)&B2l[lbB[i]] = ld8f(B2 + bgoff[i] + kc);
      }
    }
    __syncthreads();

#pragma unroll
    for (int kf = 0; kf < 2; kf++) {
      int kp = (kf * 4 + (lane >> 4)) ^ (lane & 7);
      bf16x8 af[4];
#pragma unroll
      for (int mf = 0; mf < 4; mf++) {
        int row = wm * 64 + mf * 16 + (lane & 15);
        af[mf] = *(const bf16x8*)&Al[row * 64 + kp * 8];
      }
#pragma unroll
      for (int nf = 0; nf < 2; nf++) {
        int col = wn * 32 + nf * 16 + (lane & 15);
        bf16x8 b1 = *(const bf16x8*)&B1l[col * 64 + kp * 8];
#pragma unroll
        for (int mf = 0; mf < 4; mf++)
          acc[0][mf][nf] = __builtin_amdgcn_mfma_f32_16x16x32_bf16(
              af[mf], b1, acc[0][mf][nf], 0, 0, 0);
        if (routed) {
          bf16x8 b2 = *(const bf16x8*)&B2l[col * 64 + kp * 8];
#pragma unroll
          for (int mf = 0; mf < 4; mf++)
            acc[1][mf][nf] = __builtin_amdgcn_mfma_f32_16x16x32_bf16(
                af[mf], b2, acc[1][mf][nf], 0, 0, 0);
        }
      }
    }
    __syncthreads();
  }

  // epilogue: C/D mapping col = lane&15, row = quad*4 + reg
  int quad = lane >> 4;
  int colb = n0 + wn * 32 + (lane & 15);
  short* dst = routed ? h : g;
#pragma unroll
  for (int mf = 0; mf < 4; mf++)
#pragma unroll
    for (int r = 0; r < 4; r++) {
      int srow = row0 + wm * 64 + mf * 16 + quad * 4 + r;
      if (srow >= cnt) continue;
      long ro = (long)(base + srow) * IDIM + colb;
      if (routed) {
#pragma unroll
        for (int nf = 0; nf < 2; nf++) {
          float a1 = acc[0][mf][nf][r];
          float a3 = acc[1][mf][nf][r];
          dst[ro + nf * 16] = f2bf((a1 / (1.f + __expf(-a1))) * a3);
        }
      } else {
#pragma unroll
        for (int nf = 0; nf < 2; nf++)
          dst[ro + nf * 16] = f2bf(gelu_exactish(acc[0][mf][nf][r]));
      }
    }
}

// ---- stage2: out[perm[rows]] = He@w2^T + Ge@sw2^T. BM=64 BN=64 BK=64,
// A bf16 via gll, B fp32 inline-convert, 16KB LDS, no atomics. ------------
__global__ __launch_bounds__(256, 6) void stage2(
    const short* __restrict__ h, const short* __restrict__ g,
    const float* __restrict__ w2, const float* __restrict__ sw2,
    float* __restrict__ out, const int* __restrict__ counts,
    const int* __restrict__ offsets, const int* __restrict__ nmeta,
    const int* __restrict__ te, const int* __restrict__ tr,
    const int* __restrict__ perm) {
  __shared__ short Al[64 * 64];
  __shared__ short Bl[64 * 64];
  int t = blockIdx.y;
  if (t >= nmeta[1]) return;
  int e = te[t], row0 = tr[t];
  int cnt = counts[e], base = offsets[e];
  const float* w2e = w2 + (long)e * DIM * IDIM;
  int n0 = blockIdx.x * 64;
  int tid = threadIdx.x, lane = tid & 63, w = tid >> 6;
  int wm = w >> 1, wn = w & 1;

  int aoff[2], lbA[2], bgoff[2], lbB[2];
#pragma unroll
  for (int i = 0; i < 2; i++) {
    int c = i * 256 + tid;
    int row = c >> 3, klog = (c & 7) ^ (row & 7);
    int srow = row0 + row;
    int arow = base + ((srow < cnt) ? srow : (cnt - 1));
    aoff[i] = arow * IDIM + klog * 8;
    lbA[i] = (i * 256 + w * 64) * 8;  // wave-uniform base
    bgoff[i] = (n0 + row) * IDIM + klog * 8;  // fp32 elements
    lbB[i] = c * 8;
  }

  floatx4 acc[2][2];
#pragma unroll
  for (int i = 0; i < 2; i++)
#pragma unroll
    for (int j = 0; j < 2; j++) acc[i][j] = (floatx4)0.f;

#pragma unroll
  for (int ph = 0; ph < 2; ph++) {
    const short* As = ph ? g : h;
    const float* Bf = ph ? sw2 : w2e;
    for (int kc = 0; kc < IDIM; kc += 64) {
#pragma unroll
      for (int i = 0; i < 2; i++) gll(As + aoff[i] + kc, &Al[lbA[i]]);
#pragma unroll
      for (int i = 0; i < 2; i++) {
        *(bf16x8*)&Bl[lbB[i]] = ld8f(Bf + bgoff[i] + kc);
      }
      __syncthreads();

#pragma unroll
      for (int kf = 0; kf < 2; kf++) {
        int kp = (kf * 4 + (lane >> 4)) ^ (lane & 7);
        bf16x8 af[2];
#pragma unroll
        for (int mf = 0; mf < 2; mf++) {
          int row = wm * 32 + mf * 16 + (lane & 15);
          af[mf] = *(const bf16x8*)&Al[row * 64 + kp * 8];
        }
#pragma unroll
        for (int nf = 0; nf < 2; nf++) {
          int col = wn * 32 + nf * 16 + (lane & 15);
          bf16x8 bv = *(const bf16x8*)&Bl[col * 64 + kp * 8];
#pragma unroll
          for (int mf = 0; mf < 2; mf++)
            acc[mf][nf] = __builtin_amdgcn_mfma_f32_16x16x32_bf16(
                af[mf], bv, acc[mf][nf], 0, 0, 0);
        }
      }
      __syncthreads();
    }
  }

  int quad = lane >> 4;
  int colb = n0 + wn * 32 + (lane & 15);
#pragma unroll
  for (int mf = 0; mf < 2; mf++)
#pragma unroll
    for (int r = 0; r < 4; r++) {
      int srow = row0 + wm * 32 + mf * 16 + quad * 4 + r;
      if (srow >= cnt) continue;
      long ro = (long)perm[base + srow] * DIM + colb;
#pragma unroll
      for (int nf = 0; nf < 2; nf++) out[ro + nf * 16] = acc[mf][nf][r];
    }
}

extern "C" void kernel_launch(void* const* d_in, const int* in_sizes, int n_in,
                              void* d_out, int out_size, void* d_ws, size_t ws_size,
                              hipStream_t stream) {
  const float* x = (const float*)d_in[0];
  const float* gate_w = (const float*)d_in[1];
  const float* w1 = (const float*)d_in[2];
  const float* w2 = (const float*)d_in[3];
  const float* w3 = (const float*)d_in[4];
  const float* sw1 = (const float*)d_in[5];
  const float* sw2 = (const float*)d_in[6];
  float* out = (float*)d_out;

  char* ws = (char*)d_ws;
  int* counts = (int*)ws;          // 8
  int* offsets = counts + 8;       // 8
  int* cursors = offsets + 8;      // 8
  int* nmeta = cursors + 8;        // 8
  int* te1 = nmeta + 8;            // 128
  int* tr1 = te1 + 128;            // 128
  int* te2 = tr1 + 128;            // 128
  int* tr2 = te2 + 128;            // 128
  int* expert_id = tr2 + 128;      // 4096
  int* perm = expert_id + N_TOK;   // 4096
  short* xb = (short*)(ws + 65536);        // 4 MB   [N_TOK, DIM] bf16
  short* h = xb + (size_t)N_TOK * DIM;     // 16 MB  [N_TOK, IDIM] sorted rows
  short* g = h + (size_t)N_TOK * IDIM;     // 16 MB  [N_TOK, IDIM] sorted rows

  gate_kernel<<<N_TOK / 16, 256, 0, stream>>>(x, gate_w, xb, expert_id);
  scan_scatter<<<1, 256, 0, stream>>>(expert_id, counts, offsets, cursors, nmeta,
                                      te1, tr1, te2, tr2, perm);
  stage1<<<dim3(IDIM / 64, 72), 256, 0, stream>>>(
      xb, w1, w3, sw1, h, g, counts, offsets, nmeta, te1, tr1, perm);
  stage2<<<dim3(DIM / 64, 72), 256, 0, stream>>>(
      h, g, w2, sw2, out, counts, offsets, nmeta, te2, tr2, perm);
}